// Round 10
// baseline (5459.142 us; speedup 1.0000x reference)
//
#include <hip/hip_runtime.h>
#include <hip/hip_bf16.h>

typedef __bf16 bf16_t;
typedef __bf16 bf16x8 __attribute__((ext_vector_type(8)));
typedef __bf16 bf16x4 __attribute__((ext_vector_type(4)));
typedef float  f32x4  __attribute__((ext_vector_type(4)));

#define MFMA __builtin_amdgcn_mfma_f32_16x16x32_bf16

// ---------------- workspace layout (bytes) ----------------
// WBF: bf16 [72 ntile][12 kk][64 lane][8]  qkv weights, MFMA frag order
//      ntile = h*6 + tct (tct: 0,1=q halves; 2,3=k halves; 4,5=v halves)
#define WBT_OFF   0                                   // 884736 B
// PWF: bf16 [24 ntile][12 kk][64 lane][8]  proj weights, frag order
#define PWB_OFF   (72*12*512*2)                       // 884736
// BIASL: f32 [12 h][4 mq][4 kt][64 lane][4 r]; bias[q=mq*16+(l&15)][k=kt*16+(l>>4)*4+r]
//        masked -1e30 when k>=49 or q>=49  (S^T C-frag layout)
#define BIASL_OFF (PWB_OFF + 24*12*512*2)             // 1179648; size 196608
// total ws = 1,376,256 B

// ---------------- LDS layout (bytes) ----------------
// XS: bf16 [64][384] row stride 768, XOR-swizzled          @ 0       (49152)
// per head hl (stride 9216) @ 49152 (reused each pass):
//   K  bf16 [64 tok][32 dim] stride 72   (+0,    4608)
//   VT bf16 [32 dim][64 tok] stride 144  (+4608, 4608)
// O[3]: bf16 [64 tok][128 dim] stride 272 @ 86016  (3 x 17408) — one per pass
#define L_KV   49152
#define L_OB   (L_KV + 4*9216)          // 86016
#define L_TOT  (L_OB + 3*17408)         // 138240

__global__ void prep_kernel(const float* __restrict__ qkv_w,
                            const float* __restrict__ proj_w,
                            const float* __restrict__ rpb,
                            const int*   __restrict__ rel_idx,
                            char* __restrict__ ws)
{
    const int n_wbf  = 72*12*512;    // 442368
    const int n_pwf  = 24*12*512;    // 147456
    const int n_bias = 12*4*4*64*4;  // 49152
    int idx = blockIdx.x * blockDim.x + threadIdx.x;
    if (idx < n_wbf) {
        int j = idx & 7, lane = (idx >> 3) & 63;
        int t = idx >> 9;
        int kk = t % 12, ntile = t / 12;
        int lo = lane & 15, hi = lane >> 4;
        int h = ntile / 6, tct = ntile % 6, s = tct >> 1, db = (tct & 1) << 4;
        ((bf16_t*)(ws + WBT_OFF))[idx] =
            (bf16_t)qkv_w[(s*384 + h*32 + db + lo)*384 + kk*32 + hi*8 + j];
    } else if (idx < n_wbf + n_pwf) {
        int li = idx - n_wbf;
        int j = li & 7, lane = (li >> 3) & 63;
        int t = li >> 9;
        int kk = t % 12, ntile = t / 12;
        int lo = lane & 15, hi = lane >> 4;
        ((bf16_t*)(ws + PWB_OFF))[li] =
            (bf16_t)proj_w[(ntile*16 + lo)*384 + kk*32 + hi*8 + j];
    } else if (idx < n_wbf + n_pwf + n_bias) {
        int li = idx - n_wbf - n_pwf;          // [h][mq][kt][l][r]
        int r  = li & 3;
        int l  = (li >> 2) & 63;
        int kt = (li >> 8) & 3;
        int mq = (li >> 10) & 3;
        int h  = li >> 12;
        int q  = mq*16 + (l & 15);
        int k  = kt*16 + (l >> 4)*4 + r;
        float v = (k < 49 && q < 49) ? rpb[rel_idx[q*49 + k]*12 + h] : -1e30f;
        ((float*)(ws + BIASL_OFF))[li] = v;
    }
}

static __device__ __forceinline__ unsigned pack2(float a, float b) {
    bf16_t xa = (bf16_t)a, xb = (bf16_t)b;
    unsigned short ua = __builtin_bit_cast(unsigned short, xa);
    unsigned short ub = __builtin_bit_cast(unsigned short, xb);
    return (unsigned)ua | ((unsigned)ub << 16);
}

union U8 { unsigned u[4]; bf16x8 v; };

// 512 threads => block intrinsically needs 2 waves/EU => VGPR cap is 128
// regardless of launch_bounds. Kernel is scheduled so every phase's live
// register set fits ~115: proj runs ONCE at the end (accP not live during
// passes), phase-1 prefetch ring is 2-deep.
__launch_bounds__(512, 2)
__global__ void fused3_kernel(const float* __restrict__ x,
                              const float* __restrict__ qkv_b,
                              const float* __restrict__ proj_b,
                              const char*  __restrict__ ws,
                              float* __restrict__ out)
{
    __shared__ __attribute__((aligned(16))) char smem[L_TOT];

    const int tid = threadIdx.x;
    const int lane = tid & 63, lo = lane & 15, hi = lane >> 4;
    const int w = tid >> 6;
    const int hl = w >> 1;          // head-local 0..3
    const int mh = w & 1;           // token-half (m-tiles 2mh, 2mh+1)
    const int wi = blockIdx.x;

    auto xs_addr = [&](int row, int kb) { return row*768 + (kb ^ ((row & 7) << 4)); };

    // ---- stage x (fp32 -> bf16, swizzled), zero pad rows 49..63 ----
    uint4 z4 = make_uint4(0u,0u,0u,0u);
    for (int c = tid; c < 15*48; c += 512) {
        int row = 49 + c/48, kc = c%48;
        *(uint4*)(smem + xs_addr(row, kc*16)) = z4;
    }
    const float* xw = x + (size_t)wi * (49*384);
    for (int c = tid; c < 49*48; c += 512) {
        int row = c/48, kc = c%48;
        float4 f0 = *(const float4*)(xw + row*384 + kc*8);
        float4 f1 = *(const float4*)(xw + row*384 + kc*8 + 4);
        bf16x8 t;
        t[0]=(bf16_t)f0.x; t[1]=(bf16_t)f0.y; t[2]=(bf16_t)f0.z; t[3]=(bf16_t)f0.w;
        t[4]=(bf16_t)f1.x; t[5]=(bf16_t)f1.y; t[6]=(bf16_t)f1.z; t[7]=(bf16_t)f1.w;
        *(bf16x8*)(smem + xs_addr(row, kc*16)) = t;
    }
    __syncthreads();

    const bf16_t* WBF = (const bf16_t*)(ws + WBT_OFF);
    const bf16_t* PWF = (const bf16_t*)(ws + PWB_OFF);
    const float4* bT  = (const float4*)(ws + BIASL_OFF);
    const float scale = 0.17677669529663687f; // 1/sqrt(32)
    const f32x4 zz = {0.f,0.f,0.f,0.f};
    const int sb = lo + ((hi & 1) << 5);      // exchange src-lane base

#pragma unroll 1
    for (int pass = 0; pass < 3; ++pass) {
        const int h = pass*4 + hl;
        bf16x8 bq[2];   // Q B-frags, phase1 -> phase2

        // ================= phase 1: QKV (swapped orientation) =================
        {
            const bf16_t* wq0b = WBF + (size_t)((h*6 + 0   )*12)*512 + (lane<<3);
            const bf16_t* wq1b = WBF + (size_t)((h*6 + 1   )*12)*512 + (lane<<3);
            const bf16_t* wkb  = WBF + (size_t)((h*6 + 2+mh)*12)*512 + (lane<<3);
            const bf16_t* wvb  = WBF + (size_t)((h*6 + 4+mh)*12)*512 + (lane<<3);

            f32x4 aq[2][2], ak4[4], av4[4];
#pragma unroll
            for (int i = 0; i < 2; ++i) { aq[i][0] = zz; aq[i][1] = zz; }
#pragma unroll
            for (int i = 0; i < 4; ++i) { ak4[i] = zz; av4[i] = zz; }

            bf16x8 rq0[2], rq1[2], rk[2], rv[2];   // 2-deep ring (32 regs)
#pragma unroll
            for (int t = 0; t < 2; ++t) {
                rq0[t] = *(const bf16x8*)(wq0b + (t<<9));
                rq1[t] = *(const bf16x8*)(wq1b + (t<<9));
                rk [t] = *(const bf16x8*)(wkb  + (t<<9));
                rv [t] = *(const bf16x8*)(wvb  + (t<<9));
            }
#pragma unroll
            for (int kk = 0; kk < 12; ++kk) {
                const int sl = kk & 1;
                bf16x8 xf[4];
#pragma unroll
                for (int tt = 0; tt < 4; ++tt)
                    xf[tt] = *(const bf16x8*)(smem + xs_addr(tt*16 + lo, kk*64 + hi*16));
#pragma unroll
                for (int mi = 0; mi < 2; ++mi) {
                    aq[0][mi] = MFMA(rq0[sl], xf[2*mh + mi], aq[0][mi], 0,0,0);
                    aq[1][mi] = MFMA(rq1[sl], xf[2*mh + mi], aq[1][mi], 0,0,0);
                }
#pragma unroll
                for (int tt = 0; tt < 4; ++tt) ak4[tt] = MFMA(rk[sl], xf[tt], ak4[tt], 0,0,0);
#pragma unroll
                for (int tt = 0; tt < 4; ++tt) av4[tt] = MFMA(xf[tt], rv[sl], av4[tt], 0,0,0);
                if (kk < 10) {
                    rq0[sl] = *(const bf16x8*)(wq0b + ((kk+2)<<9));
                    rq1[sl] = *(const bf16x8*)(wq1b + ((kk+2)<<9));
                    rk [sl] = *(const bf16x8*)(wkb  + ((kk+2)<<9));
                    rv [sl] = *(const bf16x8*)(wvb  + ((kk+2)<<9));
                }
            }

            // ---- Q: bias+scale, pack, in-register hi-exchange -> B-frags ----
            float4 qb0 = *(const float4*)(qkv_b + h*32 +      hi*4);
            float4 qb1 = *(const float4*)(qkv_b + h*32 + 16 + hi*4);
            unsigned pkq[2][2][2];  // [dt][mi][rp]
#pragma unroll
            for (int mi = 0; mi < 2; ++mi) {
                pkq[0][mi][0] = pack2((aq[0][mi][0]+qb0.x)*scale, (aq[0][mi][1]+qb0.y)*scale);
                pkq[0][mi][1] = pack2((aq[0][mi][2]+qb0.z)*scale, (aq[0][mi][3]+qb0.w)*scale);
                pkq[1][mi][0] = pack2((aq[1][mi][0]+qb1.x)*scale, (aq[1][mi][1]+qb1.y)*scale);
                pkq[1][mi][1] = pack2((aq[1][mi][2]+qb1.z)*scale, (aq[1][mi][3]+qb1.w)*scale);
            }
#pragma unroll
            for (int mi = 0; mi < 2; ++mi) {
                U8 u;
#pragma unroll
                for (int jp = 0; jp < 4; ++jp) {
                    const int rp = jp & 1, hf = jp >> 1;
                    const int srcl = sb + (hf << 4);
                    unsigned s0 = (unsigned)__shfl((int)pkq[0][mi][rp], srcl, 64);
                    unsigned s1 = (unsigned)__shfl((int)pkq[1][mi][rp], srcl, 64);
                    u.u[jp] = (hi >> 1) ? s1 : s0;
                }
                bq[mi] = u.v;
            }

            // ---- K: [token][dim] rows, b64 vector stores ----
            float4 kb = *(const float4*)(qkv_b + 384 + h*32 + mh*16 + hi*4);
            char* Kl = smem + L_KV + hl*9216;
#pragma unroll
            for (int tt = 0; tt < 4; ++tt) {
                bf16x4 t;
                t[0]=(bf16_t)(ak4[tt][0]+kb.x); t[1]=(bf16_t)(ak4[tt][1]+kb.y);
                t[2]=(bf16_t)(ak4[tt][2]+kb.z); t[3]=(bf16_t)(ak4[tt][3]+kb.w);
                *(bf16x4*)(Kl + (tt*16+lo)*72 + (mh*16+hi*4)*2) = t;
            }
            // ---- V: [dim][token] rows (V^T), b64 vector stores ----
            float vb = qkv_b[768 + h*32 + mh*16 + lo];
            char* Vl = Kl + 4608;
#pragma unroll
            for (int tt = 0; tt < 4; ++tt) {
                bf16x4 t;
                t[0]=(bf16_t)(av4[tt][0]+vb); t[1]=(bf16_t)(av4[tt][1]+vb);
                t[2]=(bf16_t)(av4[tt][2]+vb); t[3]=(bf16_t)(av4[tt][3]+vb);
                *(bf16x4*)(Vl + (mh*16+lo)*144 + (tt*16+hi*4)*2) = t;
            }
        }
        __syncthreads();   // bar A: QKV tiles visible

        // ================= phase 2: attention -> O buffer[pass] =================
        {
            const char* Kl = smem + L_KV + hl*9216;
            const char* Vl = Kl + 4608;
            bf16x8 akf[4];
#pragma unroll
            for (int kt = 0; kt < 4; ++kt)
                akf[kt] = *(const bf16x8*)(Kl + (kt*16+lo)*72 + hi*16);
            bf16x8 avf[2][2];
#pragma unroll
            for (int dt = 0; dt < 2; ++dt)
#pragma unroll
                for (int ks = 0; ks < 2; ++ks)
                    avf[dt][ks] = *(const bf16x8*)(Vl + (dt*16+lo)*144 + ks*64 + hi*16);

            char* Ob = smem + L_OB + pass*17408;
#pragma unroll
            for (int mi = 0; mi < 2; ++mi) {
                const int mq = mh*2 + mi;
                f32x4 st[4];
#pragma unroll
                for (int kt = 0; kt < 4; ++kt) {
                    st[kt] = MFMA(akf[kt], bq[mi], zz, 0,0,0);
                    float4 bv = bT[((h*4 + mq)*4 + kt)*64 + lane];
                    st[kt][0]+=bv.x; st[kt][1]+=bv.y; st[kt][2]+=bv.z; st[kt][3]+=bv.w;
                }
                // softmax over k: 16 local + 2 cross-hi shuffles
                float mx = fmaxf(fmaxf(fmaxf(st[0][0],st[0][1]), fmaxf(st[0][2],st[0][3])),
                                 fmaxf(fmaxf(st[1][0],st[1][1]), fmaxf(st[1][2],st[1][3])));
                mx = fmaxf(mx, fmaxf(fmaxf(fmaxf(st[2][0],st[2][1]), fmaxf(st[2][2],st[2][3])),
                                     fmaxf(fmaxf(st[3][0],st[3][1]), fmaxf(st[3][2],st[3][3]))));
                mx = fmaxf(mx, __shfl_xor(mx, 16));
                mx = fmaxf(mx, __shfl_xor(mx, 32));
                float e[4][4]; float sum = 0.f;
#pragma unroll
                for (int kt = 0; kt < 4; ++kt)
#pragma unroll
                    for (int r = 0; r < 4; ++r) { e[kt][r] = __expf(st[kt][r] - mx); sum += e[kt][r]; }
                sum += __shfl_xor(sum, 16);
                sum += __shfl_xor(sum, 32);
                float rinv = 1.0f / sum;
                unsigned pkp[4][2];
#pragma unroll
                for (int kt = 0; kt < 4; ++kt) {
                    pkp[kt][0] = pack2(e[kt][0]*rinv, e[kt][1]*rinv);
                    pkp[kt][1] = pack2(e[kt][2]*rinv, e[kt][3]*rinv);
                }
                bf16x8 bp[2];
#pragma unroll
                for (int ks = 0; ks < 2; ++ks) {
                    U8 u;
#pragma unroll
                    for (int jp = 0; jp < 4; ++jp) {
                        const int rp = jp & 1, hf = jp >> 1;
                        const int srcl = sb + (hf << 4);
                        unsigned s0 = (unsigned)__shfl((int)pkp[2*ks  ][rp], srcl, 64);
                        unsigned s1 = (unsigned)__shfl((int)pkp[2*ks+1][rp], srcl, 64);
                        u.u[jp] = (hi >> 1) ? s1 : s0;
                    }
                    bp[ks] = u.v;
                }
                // PV (O^T orientation) -> O LDS [token][dim], b64 stores
#pragma unroll
                for (int dt = 0; dt < 2; ++dt) {
                    f32x4 o = MFMA(avf[dt][0], bp[0], zz, 0,0,0);
                    o = MFMA(avf[dt][1], bp[1], o, 0,0,0);
                    bf16x4 t;
                    t[0]=(bf16_t)o[0]; t[1]=(bf16_t)o[1]; t[2]=(bf16_t)o[2]; t[3]=(bf16_t)o[3];
                    *(bf16x4*)(Ob + (mq*16+lo)*272 + (hl*32 + dt*16 + hi*4)*2) = t;
                }
            }
        }
        __syncthreads();   // bar B: O[pass] visible; KV free for next pass
    }

    // ================= final: proj GEMM over all 3 O buffers =================
    f32x4 accP[4][3];
#pragma unroll
    for (int m = 0; m < 4; ++m)
#pragma unroll
        for (int nt = 0; nt < 3; ++nt) accP[m][nt] = zz;

    {
        bf16x8 pwn[3], pwc[3];
#pragma unroll
        for (int nt = 0; nt < 3; ++nt)
            pwn[nt] = *(const bf16x8*)(PWF + ((size_t)((w*3+nt)*12 + 0) << 9) + (lane<<3));
#pragma unroll 1
        for (int kk2 = 0; kk2 < 12; ++kk2) {
#pragma unroll
            for (int nt = 0; nt < 3; ++nt) pwc[nt] = pwn[nt];
            if (kk2 < 11) {
#pragma unroll
                for (int nt = 0; nt < 3; ++nt)
                    pwn[nt] = *(const bf16x8*)(PWF + ((size_t)((w*3+nt)*12 + kk2+1) << 9) + (lane<<3));
            }
            const char* Op = smem + L_OB + (kk2 >> 2)*17408;
            const int k4 = kk2 & 3;
#pragma unroll
            for (int mp = 0; mp < 2; ++mp) {
                bf16x8 ao[2];
#pragma unroll
                for (int mi = 0; mi < 2; ++mi)
                    ao[mi] = *(const bf16x8*)(Op + ((mp*2+mi)*16+lo)*272 + k4*64 + hi*16);
#pragma unroll
                for (int nt = 0; nt < 3; ++nt)
#pragma unroll
                    for (int mi = 0; mi < 2; ++mi)
                        accP[mp*2+mi][nt] = MFMA(ao[mi], pwc[nt], accP[mp*2+mi][nt], 0,0,0);
            }
        }
    }

    // ---- epilogue: add proj bias, store fp32 ----
    float* ow = out + (size_t)wi * (49*384);
#pragma unroll
    for (int nt = 0; nt < 3; ++nt) {
        int cc = (w*3 + nt)*16 + lo;
        float pb = proj_b[cc];
#pragma unroll
        for (int m = 0; m < 4; ++m)
#pragma unroll
            for (int r = 0; r < 4; ++r) {
                int row = m*16 + hi*4 + r;
                if (row < 49) ow[row*384 + cc] = accP[m][nt][r] + pb;
            }
    }
}

extern "C" void kernel_launch(void* const* d_in, const int* in_sizes, int n_in,
                              void* d_out, int out_size, void* d_ws, size_t ws_size,
                              hipStream_t stream)
{
    const float* x      = (const float*)d_in[0];
    const float* qkv_w  = (const float*)d_in[1];
    const float* qkv_b  = (const float*)d_in[2];
    const float* proj_w = (const float*)d_in[3];
    const float* proj_b = (const float*)d_in[4];
    const float* rpb    = (const float*)d_in[5];
    const int*   rel_idx= (const int*)d_in[6];
    char* ws = (char*)d_ws;

    const int total = 72*12*512 + 24*12*512 + 12*4*4*64*4;
    prep_kernel<<<(total + 255)/256, 256, 0, stream>>>(qkv_w, proj_w, rpb, rel_idx, ws);
    fused3_kernel<<<4096, 512, 0, stream>>>(x, qkv_b, proj_b, ws, (float*)d_out);
}

// Round 11
// 665.131 us; speedup vs baseline: 8.2076x; 8.2076x over previous
//
#include <hip/hip_runtime.h>
#include <hip/hip_bf16.h>

typedef __bf16 bf16_t;
typedef __bf16 bf16x8 __attribute__((ext_vector_type(8)));
typedef __bf16 bf16x4 __attribute__((ext_vector_type(4)));
typedef float  f32x4  __attribute__((ext_vector_type(4)));

#define MFMA __builtin_amdgcn_mfma_f32_16x16x32_bf16

// ---------------- workspace layout (bytes) ----------------
// WBF: bf16 [72 ntile][12 kk][64 lane][8]  qkv weights in MFMA B-frag order
//      (ntile = h*6 + tct; tct: 0,1=q 2,3=k 4,5=v halves)
#define WBT_OFF   0                                  // 884736 B
// PWF: bf16 [24 ntile][12 kk][64 lane][8]  proj weights in B-frag order
#define PWB_OFF   (72*12*512*2)                      // 884736
// BIASL: f32 [12 h][4 mq][4 kt][64 lane][4 r]  S^T C-frag layout:
//        value = bias[q=mq*16+(l&15)][k=kt*16+(l>>4)*4+r]; -1e30 if k>=49 or q>=49
#define BIASL_OFF (PWB_OFF + 24*12*512*2)            // 1179648; 196608 B
#define QKVB_OFF  (BIASL_OFF + 12*4*4*64*4*4)        // f32 [1152] qkv bias remapped
// total ws = QKVB_OFF + 1152*4 = 1,380,864 B

// ---------------- LDS layout (bytes) ----------------
// XS: bf16 [64][384] row stride 768, XOR-swizzled        @ 0      (49152)
// per head-local hl (stride 13824) @ 49152:
//   QS bf16 [64 tok][32 dim] stride 72   (+0,    4608)
//   KS bf16 [64 tok][32 dim] stride 72   (+4608, 4608)
//   VT bf16 [32 dim][64 tok] stride 144  (+9216, 4608)
// O: bf16 [64 tok][128 dim] stride 272 @ 104448 (17408)
#define L_HEAD   49152
#define L_HSTR   13824
#define L_O      104448
#define L_TOT    121856

__global__ void prep_kernel(const float* __restrict__ qkv_w,
                            const float* __restrict__ qkv_b,
                            const float* __restrict__ proj_w,
                            const float* __restrict__ rpb,
                            const int*   __restrict__ rel_idx,
                            char* __restrict__ ws)
{
    const int n_wbf  = 72*12*512;    // 442368
    const int n_pwf  = 24*12*512;    // 147456
    const int n_bias = 12*4*4*64*4;  // 49152
    const int n_qb   = 1152;
    int idx = blockIdx.x * blockDim.x + threadIdx.x;
    if (idx < n_wbf) {
        int j = idx & 7, lane = (idx >> 3) & 63;
        int t = idx >> 9;
        int kk = t % 12, ntile = t / 12;
        int lo = lane & 15, hi = lane >> 4;
        int h = ntile / 6, tct = ntile % 6, s = tct >> 1, db = (tct & 1) << 4;
        ((bf16_t*)(ws + WBT_OFF))[idx] =
            (bf16_t)qkv_w[(s*384 + h*32 + db + lo)*384 + kk*32 + hi*8 + j];
    } else if (idx < n_wbf + n_pwf) {
        int li = idx - n_wbf;
        int j = li & 7, lane = (li >> 3) & 63;
        int t = li >> 9;
        int kk = t % 12, ntile = t / 12;
        int lo = lane & 15, hi = lane >> 4;
        ((bf16_t*)(ws + PWB_OFF))[li] =
            (bf16_t)proj_w[(ntile*16 + lo)*384 + kk*32 + hi*8 + j];
    } else if (idx < n_wbf + n_pwf + n_bias) {
        int li = idx - n_wbf - n_pwf;          // [h][mq][kt][l][r]  (S^T layout)
        int r  = li & 3;
        int l  = (li >> 2) & 63;
        int kt = (li >> 8) & 3;
        int mq = (li >> 10) & 3;
        int h  = li >> 12;
        int q  = mq*16 + (l & 15);
        int k  = kt*16 + (l >> 4)*4 + r;
        float v = (k < 49 && q < 49) ? rpb[rel_idx[q*49 + k]*12 + h] : -1e30f;
        ((float*)(ws + BIASL_OFF))[li] = v;
    } else if (idx < n_wbf + n_pwf + n_bias + n_qb) {
        int i = idx - n_wbf - n_pwf - n_bias;  // h*96 + c
        int h = i / 96, c = i % 96;
        int s = c >> 5, cc = c & 31;
        ((float*)(ws + QKVB_OFF))[i] = qkv_b[s*384 + h*32 + cc];
    }
}

static __device__ __forceinline__ unsigned pack2(float a, float b) {
    bf16_t xa = (bf16_t)a, xb = (bf16_t)b;
    unsigned short ua = __builtin_bit_cast(unsigned short, xa);
    unsigned short ub = __builtin_bit_cast(unsigned short, xb);
    return (unsigned)ua | ((unsigned)ub << 16);
}

union U8 { unsigned u[4]; bf16x8 v; };

// r6 base (702us) with phase 2 replaced by the r7-proven swapped-QK^T
// in-register softmax (Q sourced from LDS, no P buffer, 2 barriers/pass).
__launch_bounds__(512, 2)
__global__ void fused4_kernel(const float* __restrict__ x,
                              const float* __restrict__ proj_b,
                              const char*  __restrict__ ws,
                              float* __restrict__ out)
{
    __shared__ __attribute__((aligned(16))) char smem[L_TOT];

    const int tid = threadIdx.x;
    const int lane = tid & 63, lo = lane & 15, hi = lane >> 4;
    const int w = tid >> 6;
    const int wi = blockIdx.x;

    auto xs_addr = [&](int row, int kb) { return row*768 + (kb ^ ((row & 7) << 4)); };

    // ---- stage x (fp32 -> bf16, swizzled), zero pad rows 49..63 ----
    uint4 z4 = make_uint4(0u,0u,0u,0u);
    for (int c = tid; c < 15*48; c += 512) {
        int row = 49 + c/48, kc = c%48;
        *(uint4*)(smem + xs_addr(row, kc*16)) = z4;
    }
    const float* xw = x + (size_t)wi * (49*384);
    for (int c = tid; c < 49*48; c += 512) {
        int row = c/48, kc = c%48;
        float4 f0 = *(const float4*)(xw + row*384 + kc*8);
        float4 f1 = *(const float4*)(xw + row*384 + kc*8 + 4);
        bf16x8 t;
        t[0]=(bf16_t)f0.x; t[1]=(bf16_t)f0.y; t[2]=(bf16_t)f0.z; t[3]=(bf16_t)f0.w;
        t[4]=(bf16_t)f1.x; t[5]=(bf16_t)f1.y; t[6]=(bf16_t)f1.z; t[7]=(bf16_t)f1.w;
        *(bf16x8*)(smem + xs_addr(row, kc*16)) = t;
    }
    __syncthreads();

    const bf16_t* WBF   = (const bf16_t*)(ws + WBT_OFF);
    const bf16_t* PWF   = (const bf16_t*)(ws + PWB_OFF);
    const float4* bT    = (const float4*)(ws + BIASL_OFF);
    const float*  biasQ = (const float*)(ws + QKVB_OFF);
    const float scale = 0.17677669529663687f; // 1/sqrt(32)
    const f32x4 zz = {0.f,0.f,0.f,0.f};
    const int sb = lo + ((hi & 1) << 5);      // exchange src-lane base

    f32x4 accP[4][3];
#pragma unroll
    for (int m = 0; m < 4; ++m)
#pragma unroll
        for (int nt = 0; nt < 3; ++nt) accP[m][nt] = zz;

    const int hl_a = w >> 1;          // attention: head-local for this wave
    const int mh   = w & 1;           // attention: m-half (m-tiles 2mh, 2mh+1)

#pragma unroll 1
    for (int pass = 0; pass < 3; ++pass) {
        // ======== phase 1: QKV GEMM for heads 4*pass .. 4*pass+3 (r6 verbatim) ========
        {
            const bf16_t* bb = WBF + (size_t)(pass*8 + w)*(3*12*512) + (lane << 3);
            f32x4 acc[4][3];
#pragma unroll
            for (int m = 0; m < 4; ++m)
#pragma unroll
                for (int nt = 0; nt < 3; ++nt) acc[m][nt] = zz;

            bf16x8 br[3][3];
#pragma unroll
            for (int k = 0; k < 2; ++k)
#pragma unroll
                for (int nt = 0; nt < 3; ++nt)
                    br[k][nt] = *(const bf16x8*)(bb + ((nt*12 + k) << 9));

#pragma unroll
            for (int kk = 0; kk < 12; ++kk) {
                if (kk < 10) {
#pragma unroll
                    for (int nt = 0; nt < 3; ++nt)
                        br[(kk+2)%3][nt] = *(const bf16x8*)(bb + ((nt*12 + kk+2) << 9));
                }
                bf16x8 a[4];
#pragma unroll
                for (int m = 0; m < 4; ++m)
                    a[m] = *(const bf16x8*)(smem + xs_addr(m*16 + lo, kk*64 + hi*16));
#pragma unroll
                for (int nt = 0; nt < 3; ++nt)
#pragma unroll
                    for (int m = 0; m < 4; ++m)
                        acc[m][nt] = MFMA(a[m], br[kk%3][nt], acc[m][nt], 0,0,0);
            }

            // epilogue -> LDS QS/KS rows stride 72, V^T rows stride 144 (r6 verbatim)
#pragma unroll
            for (int nt = 0; nt < 3; ++nt) {
                const int ntl = w*3 + nt;             // 0..23 within pass
                const int hl = ntl / 6, tct = ntl % 6;
                const int s = tct >> 1, db = (tct & 1) << 4;
                float bq = biasQ[(pass*24 + ntl)*16 + lo];
                char* hb = smem + L_HEAD + hl*L_HSTR;
                if (s == 0) {
#pragma unroll
                    for (int m = 0; m < 4; ++m)
#pragma unroll
                        for (int r = 0; r < 4; ++r)
                            *(bf16_t*)(hb + (m*16 + hi*4 + r)*72 + (db + lo)*2) =
                                (bf16_t)((acc[m][nt][r] + bq) * scale);
                } else if (s == 1) {
#pragma unroll
                    for (int m = 0; m < 4; ++m)
#pragma unroll
                        for (int r = 0; r < 4; ++r)
                            *(bf16_t*)(hb + 4608 + (m*16 + hi*4 + r)*72 + (db + lo)*2) =
                                (bf16_t)(acc[m][nt][r] + bq);
                } else {
#pragma unroll
                    for (int m = 0; m < 4; ++m) {
                        bf16x4 p;
#pragma unroll
                        for (int r = 0; r < 4; ++r) p[r] = (bf16_t)(acc[m][nt][r] + bq);
                        *(bf16x4*)(hb + 9216 + (db + lo)*144 + (m*16 + hi*4)*2) = p;
                    }
                }
            }
        }
        __syncthreads();   // bar A: QKV tiles visible

        // ======== phase 2: attention, swapped QK^T, in-register softmax ========
        {
            const int h = pass*4 + hl_a;
            const char* Ql = smem + L_HEAD + hl_a*L_HSTR;
            const char* Kl = Ql + 4608;
            const char* Vl = Ql + 9216;
            char* Ob = smem + L_O;

            bf16x8 akf[4];
#pragma unroll
            for (int kt = 0; kt < 4; ++kt)
                akf[kt] = *(const bf16x8*)(Kl + (kt*16+lo)*72 + hi*16);

#pragma unroll
            for (int mi = 0; mi < 2; ++mi) {
                const int mq = mh*2 + mi;
                // Q as B-frag: col = query token mq*16+lo, k = dim hi*8..+7
                bf16x8 qf = *(const bf16x8*)(Ql + (mq*16+lo)*72 + hi*16);
                f32x4 st[4];
#pragma unroll
                for (int kt = 0; kt < 4; ++kt) {
                    st[kt] = MFMA(akf[kt], qf, zz, 0,0,0);
                    float4 bv = bT[((h*4 + mq)*4 + kt)*64 + lane];
                    st[kt][0]+=bv.x; st[kt][1]+=bv.y; st[kt][2]+=bv.z; st[kt][3]+=bv.w;
                }
                // softmax over k: 15 local max + 2 shuffles, exp in place
                float mx = fmaxf(fmaxf(fmaxf(st[0][0],st[0][1]), fmaxf(st[0][2],st[0][3])),
                                 fmaxf(fmaxf(st[1][0],st[1][1]), fmaxf(st[1][2],st[1][3])));
                mx = fmaxf(mx, fmaxf(fmaxf(fmaxf(st[2][0],st[2][1]), fmaxf(st[2][2],st[2][3])),
                                     fmaxf(fmaxf(st[3][0],st[3][1]), fmaxf(st[3][2],st[3][3]))));
                mx = fmaxf(mx, __shfl_xor(mx, 16));
                mx = fmaxf(mx, __shfl_xor(mx, 32));
                float sum = 0.f;
#pragma unroll
                for (int kt = 0; kt < 4; ++kt)
#pragma unroll
                    for (int r = 0; r < 4; ++r) { st[kt][r] = __expf(st[kt][r] - mx); sum += st[kt][r]; }
                sum += __shfl_xor(sum, 16);
                sum += __shfl_xor(sum, 32);
                float rinv = 1.0f / sum;
                unsigned pkp[4][2];
#pragma unroll
                for (int kt = 0; kt < 4; ++kt) {
                    pkp[kt][0] = pack2(st[kt][0]*rinv, st[kt][1]*rinv);
                    pkp[kt][1] = pack2(st[kt][2]*rinv, st[kt][3]*rinv);
                }
                // exchange across hi pairs -> P^T B-frags (r7 verbatim)
                bf16x8 bp[2];
#pragma unroll
                for (int ks = 0; ks < 2; ++ks) {
                    U8 u;
#pragma unroll
                    for (int jp = 0; jp < 4; ++jp) {
                        const int rp = jp & 1, hf = jp >> 1;
                        const int srcl = sb + (hf << 4);
                        unsigned s0 = (unsigned)__shfl((int)pkp[2*ks  ][rp], srcl, 64);
                        unsigned s1 = (unsigned)__shfl((int)pkp[2*ks+1][rp], srcl, 64);
                        u.u[jp] = (hi >> 1) ? s1 : s0;
                    }
                    bp[ks] = u.v;
                }
                // PV (O^T orientation) -> O LDS [token][dim], b64 stores
#pragma unroll
                for (int dt = 0; dt < 2; ++dt) {
                    bf16x8 av0 = *(const bf16x8*)(Vl + (dt*16+lo)*144 +      hi*16);
                    bf16x8 av1 = *(const bf16x8*)(Vl + (dt*16+lo)*144 + 64 + hi*16);
                    f32x4 o = MFMA(av0, bp[0], zz, 0,0,0);
                    o = MFMA(av1, bp[1], o, 0,0,0);
                    bf16x4 t;
                    t[0]=(bf16_t)o[0]; t[1]=(bf16_t)o[1]; t[2]=(bf16_t)o[2]; t[3]=(bf16_t)o[3];
                    *(bf16x4*)(Ob + (mq*16+lo)*272 + (hl_a*32 + dt*16 + hi*4)*2) = t;
                }
            }
        }
        __syncthreads();   // bar B: O visible

        // ======== phase 3: proj partial accumulation (r6 verbatim) ========
        {
            bf16x8 pj[2][3];
#pragma unroll
            for (int nt = 0; nt < 3; ++nt)
                pj[0][nt] = *(const bf16x8*)(PWF + ((size_t)((w*3+nt)*12 + pass*4) << 9) + (lane<<3));
#pragma unroll
            for (int kk2 = 0; kk2 < 4; ++kk2) {
                if (kk2 < 3) {
#pragma unroll
                    for (int nt = 0; nt < 3; ++nt)
                        pj[(kk2+1)&1][nt] = *(const bf16x8*)(PWF + ((size_t)((w*3+nt)*12 + pass*4 + kk2+1) << 9) + (lane<<3));
                }
                bf16x8 ao[4];
#pragma unroll
                for (int m = 0; m < 4; ++m)
                    ao[m] = *(const bf16x8*)(smem + L_O + (m*16 + lo)*272 + kk2*64 + hi*16);
#pragma unroll
                for (int nt = 0; nt < 3; ++nt)
#pragma unroll
                    for (int m = 0; m < 4; ++m)
                        accP[m][nt] = MFMA(ao[m], pj[kk2&1][nt], accP[m][nt], 0,0,0);
            }
        }
        // no end-of-pass barrier: next phase 1 writes only XS-disjoint KV/Q areas,
        // whose previous readers (phase 2) finished before bar B; O's next writer
        // (phase 2 of pass+1) is fenced by bar A of pass+1.
    }

    // ---- epilogue: add proj bias, store fp32 ----
    float* ow = out + (size_t)wi * (49*384);
#pragma unroll
    for (int nt = 0; nt < 3; ++nt) {
        int cc = (w*3 + nt)*16 + lo;
        float pb = proj_b[cc];
#pragma unroll
        for (int m = 0; m < 4; ++m)
#pragma unroll
            for (int r = 0; r < 4; ++r) {
                int row = m*16 + hi*4 + r;
                if (row < 49) ow[row*384 + cc] = accP[m][nt][r] + pb;
            }
    }
}

extern "C" void kernel_launch(void* const* d_in, const int* in_sizes, int n_in,
                              void* d_out, int out_size, void* d_ws, size_t ws_size,
                              hipStream_t stream)
{
    const float* x      = (const float*)d_in[0];
    const float* qkv_w  = (const float*)d_in[1];
    const float* qkv_b  = (const float*)d_in[2];
    const float* proj_w = (const float*)d_in[3];
    const float* proj_b = (const float*)d_in[4];
    const float* rpb    = (const float*)d_in[5];
    const int*   rel_idx= (const int*)d_in[6];
    char* ws = (char*)d_ws;

    const int total = 72*12*512 + 24*12*512 + 12*4*4*64*4 + 1152;
    prep_kernel<<<(total + 255)/256, 256, 0, stream>>>(qkv_w, qkv_b, proj_w, rpb, rel_idx, ws);
    fused4_kernel<<<4096, 512, 0, stream>>>(x, proj_b, ws, (float*)d_out);
}

// Round 12
// 633.060 us; speedup vs baseline: 8.6234x; 1.0507x over previous
//
#include <hip/hip_runtime.h>
#include <hip/hip_bf16.h>

typedef __bf16 bf16_t;
typedef __bf16 bf16x8 __attribute__((ext_vector_type(8)));
typedef __bf16 bf16x4 __attribute__((ext_vector_type(4)));
typedef float  f32x4  __attribute__((ext_vector_type(4)));

#define MFMA __builtin_amdgcn_mfma_f32_16x16x32_bf16

// ---------------- workspace layout (bytes) ----------------
// WBF: bf16 [72 ntile][12 kk][64 lane][8]  qkv weights, MFMA frag order
//      (ntile = h*6 + tct; tct: 0,1=q 2,3=k 4,5=v halves)
#define WBT_OFF   0                                  // 884736 B
// PWF: bf16 [24 ntile][12 kk][64 lane][8]  proj weights, frag order
#define PWB_OFF   (72*12*512*2)                      // 884736
// BIASL: f32 [12 h][4 mq][4 kt][64 lane][4 r]  S^T C-frag layout:
//        bias[q=mq*16+(l&15)][k=kt*16+(l>>4)*4+r]; -1e30 if k>=49 or q>=49
#define BIASL_OFF (PWB_OFF + 24*12*512*2)            // 1179648; 196608 B
// O: bf16 [200704 tok][384]  attention output (flat token space, no pad)
#define O_OFF     1380864
#define O_BYTES   (200704ULL*384*2)                  // 154,140,672

__global__ void prep_kernel(const float* __restrict__ qkv_w,
                            const float* __restrict__ proj_w,
                            const float* __restrict__ rpb,
                            const int*   __restrict__ rel_idx,
                            char* __restrict__ ws)
{
    const int n_wbf  = 72*12*512;    // 442368
    const int n_pwf  = 24*12*512;    // 147456
    const int n_bias = 12*4*4*64*4;  // 49152
    int idx = blockIdx.x * blockDim.x + threadIdx.x;
    if (idx < n_wbf) {
        int j = idx & 7, lane = (idx >> 3) & 63;
        int t = idx >> 9;
        int kk = t % 12, ntile = t / 12;
        int lo = lane & 15, hi = lane >> 4;
        int h = ntile / 6, tct = ntile % 6, s = tct >> 1, db = (tct & 1) << 4;
        ((bf16_t*)(ws + WBT_OFF))[idx] =
            (bf16_t)qkv_w[(s*384 + h*32 + db + lo)*384 + kk*32 + hi*8 + j];
    } else if (idx < n_wbf + n_pwf) {
        int li = idx - n_wbf;
        int j = li & 7, lane = (li >> 3) & 63;
        int t = li >> 9;
        int kk = t % 12, ntile = t / 12;
        int lo = lane & 15, hi = lane >> 4;
        ((bf16_t*)(ws + PWB_OFF))[li] =
            (bf16_t)proj_w[(ntile*16 + lo)*384 + kk*32 + hi*8 + j];
    } else if (idx < n_wbf + n_pwf + n_bias) {
        int li = idx - n_wbf - n_pwf;          // [h][mq][kt][l][r]  (S^T layout)
        int r  = li & 3;
        int l  = (li >> 2) & 63;
        int kt = (li >> 8) & 3;
        int mq = (li >> 10) & 3;
        int h  = li >> 12;
        int q  = mq*16 + (l & 15);
        int k  = kt*16 + (l >> 4)*4 + r;
        float v = (k < 49 && q < 49) ? rpb[rel_idx[q*49 + k]*12 + h] : -1e30f;
        ((float*)(ws + BIASL_OFF))[li] = v;
    }
}

static __device__ __forceinline__ unsigned pack2(float a, float b) {
    bf16_t xa = (bf16_t)a, xb = (bf16_t)b;
    unsigned short ua = __builtin_bit_cast(unsigned short, xa);
    unsigned short ub = __builtin_bit_cast(unsigned short, xb);
    return (unsigned)ua | ((unsigned)ub << 16);
}

union U8 { unsigned u[4]; bf16x8 v; };

// ---------------- kernel A LDS layout ----------------
// XS: bf16 [49][384] row stride 768, XOR-swizzled  @ 0     (37632)
// ZROW: 768 B of zeros (pad-token source)          @ 37632
// per head hl (stride 9216) @ 38400:
//   K  bf16 [64 tok][32 dim] stride 72   (+0,    4608)
//   VT bf16 [32 dim][64 tok] stride 144  (+4608, 4608)
#define ZROW    37632
#define L_KV    38400
#define L_TOTA  75264      // 2 blocks/CU (150528 <= 163840)

// QKV + attention. O written straight to ws (bf16 [tok][384]).
__launch_bounds__(512, 4)
__global__ void qkva_kernel(const float* __restrict__ x,
                            const float* __restrict__ qkv_b,
                            char* __restrict__ ws)
{
    __shared__ __attribute__((aligned(16))) char smem[L_TOTA];

    const int tid = threadIdx.x;
    const int lane = tid & 63, lo = lane & 15, hi = lane >> 4;
    const int w = tid >> 6;
    const int hl = w >> 1;          // head-local 0..3
    const int mh = w & 1;           // token-half (m-tiles 2mh, 2mh+1)
    const int wi = blockIdx.x;

    auto xs_addr = [&](int row, int kb) { return row*768 + (kb ^ ((row & 7) << 4)); };
    // X A-frag load; tile tt=3 rows 49..63 come from the zero row (row 48 for lo==0).
    // xs_addr(48,kb) = 36864+kb (48&7==0, no xor).
    auto ldx = [&](int tt, int kb) -> bf16x8 {
        if (tt == 3)
            return *(const bf16x8*)(smem + ((lo == 0) ? (36864 + kb) : (ZROW + kb)));
        return *(const bf16x8*)(smem + xs_addr(tt*16 + lo, kb));
    };

    // ---- stage x (fp32 -> bf16, swizzled, 49 rows) + zero row ----
    if (tid < 48) *(uint4*)(smem + ZROW + tid*16) = make_uint4(0u,0u,0u,0u);
    const float* xw = x + (size_t)wi * (49*384);
    for (int c = tid; c < 49*48; c += 512) {
        int row = c/48, kc = c%48;
        float4 f0 = *(const float4*)(xw + row*384 + kc*8);
        float4 f1 = *(const float4*)(xw + row*384 + kc*8 + 4);
        bf16x8 t;
        t[0]=(bf16_t)f0.x; t[1]=(bf16_t)f0.y; t[2]=(bf16_t)f0.z; t[3]=(bf16_t)f0.w;
        t[4]=(bf16_t)f1.x; t[5]=(bf16_t)f1.y; t[6]=(bf16_t)f1.z; t[7]=(bf16_t)f1.w;
        *(bf16x8*)(smem + xs_addr(row, kc*16)) = t;
    }
    __syncthreads();

    const bf16_t* WBF = (const bf16_t*)(ws + WBT_OFF);
    const float4* bT  = (const float4*)(ws + BIASL_OFF);
    bf16_t* Og = (bf16_t*)(ws + O_OFF);
    const float scale = 0.17677669529663687f; // 1/sqrt(32)
    const f32x4 zz = {0.f,0.f,0.f,0.f};
    const int sb = lo + ((hi & 1) << 5);      // exchange src-lane base

#pragma unroll 1
    for (int pass = 0; pass < 3; ++pass) {
        const int h = pass*4 + hl;
        bf16x8 bq[2];   // Q B-frags, phase1 -> phase2
        char* Kl = smem + L_KV + hl*9216;
        char* Vl = Kl + 4608;

        // ===== phase 1a: K,V (half mh) over all tokens -> LDS =====
        {
            const bf16_t* wkb = WBF + (size_t)((h*6 + 2+mh)*12)*512 + (lane<<3);
            const bf16_t* wvb = WBF + (size_t)((h*6 + 4+mh)*12)*512 + (lane<<3);
            f32x4 ak4[4], av4[4];
#pragma unroll
            for (int i = 0; i < 4; ++i) { ak4[i] = zz; av4[i] = zz; }
            bf16x8 rk[3], rv[3];
#pragma unroll
            for (int t = 0; t < 3; ++t) {
                rk[t] = *(const bf16x8*)(wkb + (t<<9));
                rv[t] = *(const bf16x8*)(wvb + (t<<9));
            }
#pragma unroll
            for (int kk = 0; kk < 12; ++kk) {
                const int sl = kk % 3;
                const int kb = kk*64 + hi*16;
                bf16x8 xf[4];
#pragma unroll
                for (int tt = 0; tt < 4; ++tt) xf[tt] = ldx(tt, kb);
#pragma unroll
                for (int tt = 0; tt < 4; ++tt) ak4[tt] = MFMA(rk[sl], xf[tt], ak4[tt], 0,0,0);
#pragma unroll
                for (int tt = 0; tt < 4; ++tt) av4[tt] = MFMA(xf[tt], rv[sl], av4[tt], 0,0,0);
                if (kk < 9) {
                    rk[sl] = *(const bf16x8*)(wkb + ((kk+3)<<9));
                    rv[sl] = *(const bf16x8*)(wvb + ((kk+3)<<9));
                }
            }
            // K: [token][dim] rows, b64 stores
            float4 kb4 = *(const float4*)(qkv_b + 384 + h*32 + mh*16 + hi*4);
#pragma unroll
            for (int tt = 0; tt < 4; ++tt) {
                bf16x4 t;
                t[0]=(bf16_t)(ak4[tt][0]+kb4.x); t[1]=(bf16_t)(ak4[tt][1]+kb4.y);
                t[2]=(bf16_t)(ak4[tt][2]+kb4.z); t[3]=(bf16_t)(ak4[tt][3]+kb4.w);
                *(bf16x4*)(Kl + (tt*16+lo)*72 + (mh*16+hi*4)*2) = t;
            }
            // V: [dim][token] rows (V^T), b64 stores
            float vb = qkv_b[768 + h*32 + mh*16 + lo];
#pragma unroll
            for (int tt = 0; tt < 4; ++tt) {
                bf16x4 t;
                t[0]=(bf16_t)(av4[tt][0]+vb); t[1]=(bf16_t)(av4[tt][1]+vb);
                t[2]=(bf16_t)(av4[tt][2]+vb); t[3]=(bf16_t)(av4[tt][3]+vb);
                *(bf16x4*)(Vl + (mh*16+lo)*144 + (tt*16+hi*4)*2) = t;
            }
        }

        // ===== phase 1b: Q (both halves, own 2 token tiles) -> registers =====
        {
            const bf16_t* wq0b = WBF + (size_t)((h*6 + 0)*12)*512 + (lane<<3);
            const bf16_t* wq1b = WBF + (size_t)((h*6 + 1)*12)*512 + (lane<<3);
            f32x4 aq[2][2];
#pragma unroll
            for (int i = 0; i < 2; ++i) { aq[i][0] = zz; aq[i][1] = zz; }
            bf16x8 rq0[3], rq1[3];
#pragma unroll
            for (int t = 0; t < 3; ++t) {
                rq0[t] = *(const bf16x8*)(wq0b + (t<<9));
                rq1[t] = *(const bf16x8*)(wq1b + (t<<9));
            }
#pragma unroll
            for (int kk = 0; kk < 12; ++kk) {
                const int sl = kk % 3;
                const int kb = kk*64 + hi*16;
                bf16x8 x0 = (mh == 0) ? ldx(0, kb) : ldx(2, kb);
                bf16x8 x1 = (mh == 0) ? ldx(1, kb) : ldx(3, kb);
                aq[0][0] = MFMA(rq0[sl], x0, aq[0][0], 0,0,0);
                aq[0][1] = MFMA(rq0[sl], x1, aq[0][1], 0,0,0);
                aq[1][0] = MFMA(rq1[sl], x0, aq[1][0], 0,0,0);
                aq[1][1] = MFMA(rq1[sl], x1, aq[1][1], 0,0,0);
                if (kk < 9) {
                    rq0[sl] = *(const bf16x8*)(wq0b + ((kk+3)<<9));
                    rq1[sl] = *(const bf16x8*)(wq1b + ((kk+3)<<9));
                }
            }
            // bias+scale, pack, in-register hi-exchange -> B-frags (r7 verbatim)
            float4 qb0 = *(const float4*)(qkv_b + h*32 +      hi*4);
            float4 qb1 = *(const float4*)(qkv_b + h*32 + 16 + hi*4);
            unsigned pkq[2][2][2];
#pragma unroll
            for (int mi = 0; mi < 2; ++mi) {
                pkq[0][mi][0] = pack2((aq[0][mi][0]+qb0.x)*scale, (aq[0][mi][1]+qb0.y)*scale);
                pkq[0][mi][1] = pack2((aq[0][mi][2]+qb0.z)*scale, (aq[0][mi][3]+qb0.w)*scale);
                pkq[1][mi][0] = pack2((aq[1][mi][0]+qb1.x)*scale, (aq[1][mi][1]+qb1.y)*scale);
                pkq[1][mi][1] = pack2((aq[1][mi][2]+qb1.z)*scale, (aq[1][mi][3]+qb1.w)*scale);
            }
#pragma unroll
            for (int mi = 0; mi < 2; ++mi) {
                U8 u;
#pragma unroll
                for (int jp = 0; jp < 4; ++jp) {
                    const int rp = jp & 1, hf = jp >> 1;
                    const int srcl = sb + (hf << 4);
                    unsigned s0 = (unsigned)__shfl((int)pkq[0][mi][rp], srcl, 64);
                    unsigned s1 = (unsigned)__shfl((int)pkq[1][mi][rp], srcl, 64);
                    u.u[jp] = (hi >> 1) ? s1 : s0;
                }
                bq[mi] = u.v;
            }
        }
        __syncthreads();   // bar A: K/V tiles visible

        // ===== phase 2: attention, in-register softmax, O -> global =====
        {
            bf16x8 akf[4];
#pragma unroll
            for (int kt = 0; kt < 4; ++kt)
                akf[kt] = *(const bf16x8*)(Kl + (kt*16+lo)*72 + hi*16);
            bf16x8 avf[2][2];
#pragma unroll
            for (int dt = 0; dt < 2; ++dt)
#pragma unroll
                for (int ks = 0; ks < 2; ++ks)
                    avf[dt][ks] = *(const bf16x8*)(Vl + (dt*16+lo)*144 + ks*64 + hi*16);
            __syncthreads();   // bar B: all K/V reads done -> next pass may overwrite

#pragma unroll
            for (int mi = 0; mi < 2; ++mi) {
                const int mq = mh*2 + mi;
                f32x4 st[4];
#pragma unroll
                for (int kt = 0; kt < 4; ++kt) {
                    st[kt] = MFMA(akf[kt], bq[mi], zz, 0,0,0);
                    float4 bv = bT[((h*4 + mq)*4 + kt)*64 + lane];
                    st[kt][0]+=bv.x; st[kt][1]+=bv.y; st[kt][2]+=bv.z; st[kt][3]+=bv.w;
                }
                float mx = fmaxf(fmaxf(fmaxf(st[0][0],st[0][1]), fmaxf(st[0][2],st[0][3])),
                                 fmaxf(fmaxf(st[1][0],st[1][1]), fmaxf(st[1][2],st[1][3])));
                mx = fmaxf(mx, fmaxf(fmaxf(fmaxf(st[2][0],st[2][1]), fmaxf(st[2][2],st[2][3])),
                                     fmaxf(fmaxf(st[3][0],st[3][1]), fmaxf(st[3][2],st[3][3]))));
                mx = fmaxf(mx, __shfl_xor(mx, 16));
                mx = fmaxf(mx, __shfl_xor(mx, 32));
                float sum = 0.f;
#pragma unroll
                for (int kt = 0; kt < 4; ++kt)
#pragma unroll
                    for (int r = 0; r < 4; ++r) { st[kt][r] = __expf(st[kt][r] - mx); sum += st[kt][r]; }
                sum += __shfl_xor(sum, 16);
                sum += __shfl_xor(sum, 32);
                float rinv = 1.0f / sum;
                unsigned pkp[4][2];
#pragma unroll
                for (int kt = 0; kt < 4; ++kt) {
                    pkp[kt][0] = pack2(st[kt][0]*rinv, st[kt][1]*rinv);
                    pkp[kt][1] = pack2(st[kt][2]*rinv, st[kt][3]*rinv);
                }
                bf16x8 bp[2];
#pragma unroll
                for (int ks = 0; ks < 2; ++ks) {
                    U8 u;
#pragma unroll
                    for (int jp = 0; jp < 4; ++jp) {
                        const int rp = jp & 1, hf = jp >> 1;
                        const int srcl = sb + (hf << 4);
                        unsigned s0 = (unsigned)__shfl((int)pkp[2*ks  ][rp], srcl, 64);
                        unsigned s1 = (unsigned)__shfl((int)pkp[2*ks+1][rp], srcl, 64);
                        u.u[jp] = (hi >> 1) ? s1 : s0;
                    }
                    bp[ks] = u.v;
                }
                // PV (O^T orientation) -> global O [tok][384], b64 stores
                const int tok = mq*16 + lo;
#pragma unroll
                for (int dt = 0; dt < 2; ++dt) {
                    f32x4 o = MFMA(avf[dt][0], bp[0], zz, 0,0,0);
                    o = MFMA(avf[dt][1], bp[1], o, 0,0,0);
                    if (tok < 49) {
                        bf16x4 t;
                        t[0]=(bf16_t)o[0]; t[1]=(bf16_t)o[1]; t[2]=(bf16_t)o[2]; t[3]=(bf16_t)o[3];
                        *(bf16x4*)(Og + ((size_t)wi*49 + tok)*384 + h*32 + dt*16 + hi*4) = t;
                    }
                }
            }
        }
        // no trailing barrier: bar B already fenced K/V reuse; XS is read-only
    }
}

// proj GEMM: out[tok][384] = O[tok][384] @ PW^T + b. 1 block = 64 tokens.
__launch_bounds__(512, 4)
__global__ void proj_kernel(const float* __restrict__ proj_b,
                            const char* __restrict__ ws,
                            float* __restrict__ out)
{
    __shared__ __attribute__((aligned(16))) char smem[49152];

    const int tid = threadIdx.x;
    const int lane = tid & 63, lo = lane & 15, hi = lane >> 4;
    const int w = tid >> 6;
    const int mb = blockIdx.x;

    auto xs_addr = [&](int row, int kb) { return row*768 + (kb ^ ((row & 7) << 4)); };

    const bf16_t* O = (const bf16_t*)(ws + O_OFF) + (size_t)mb*64*384;
    for (int c = tid; c < 64*48; c += 512) {
        int row = c/48, kc = c%48;
        uint4 d = *(const uint4*)(O + row*384 + kc*8);
        *(uint4*)(smem + xs_addr(row, kc*16)) = d;
    }
    __syncthreads();

    const bf16_t* PWF = (const bf16_t*)(ws + PWB_OFF);
    const bf16_t* bb  = PWF + (size_t)w*(3*12*512) + (lane << 3);
    const f32x4 zz = {0.f,0.f,0.f,0.f};

    f32x4 acc[4][3];
#pragma unroll
    for (int m = 0; m < 4; ++m)
#pragma unroll
        for (int nt = 0; nt < 3; ++nt) acc[m][nt] = zz;

    bf16x8 pj[2][3];
#pragma unroll
    for (int nt = 0; nt < 3; ++nt)
        pj[0][nt] = *(const bf16x8*)(bb + ((nt*12 + 0) << 9));
#pragma unroll
    for (int kk = 0; kk < 12; ++kk) {
        if (kk < 11) {
#pragma unroll
            for (int nt = 0; nt < 3; ++nt)
                pj[(kk+1)&1][nt] = *(const bf16x8*)(bb + ((nt*12 + kk+1) << 9));
        }
        bf16x8 a[4];
#pragma unroll
        for (int m = 0; m < 4; ++m)
            a[m] = *(const bf16x8*)(smem + xs_addr(m*16 + lo, kk*64 + hi*16));
#pragma unroll
        for (int nt = 0; nt < 3; ++nt)
#pragma unroll
            for (int m = 0; m < 4; ++m)
                acc[m][nt] = MFMA(a[m], pj[kk&1][nt], acc[m][nt], 0,0,0);
    }

    float* ow = out + (size_t)mb*64*384;
#pragma unroll
    for (int nt = 0; nt < 3; ++nt) {
        int cc = (w*3 + nt)*16 + lo;
        float pb = proj_b[cc];
#pragma unroll
        for (int m = 0; m < 4; ++m)
#pragma unroll
            for (int r = 0; r < 4; ++r)
                ow[(m*16 + hi*4 + r)*384 + cc] = acc[m][nt][r] + pb;
    }
}

extern "C" void kernel_launch(void* const* d_in, const int* in_sizes, int n_in,
                              void* d_out, int out_size, void* d_ws, size_t ws_size,
                              hipStream_t stream)
{
    const float* x      = (const float*)d_in[0];
    const float* qkv_w  = (const float*)d_in[1];
    const float* qkv_b  = (const float*)d_in[2];
    const float* proj_w = (const float*)d_in[3];
    const float* proj_b = (const float*)d_in[4];
    const float* rpb    = (const float*)d_in[5];
    const int*   rel_idx= (const int*)d_in[6];
    char* ws = (char*)d_ws;

    const int total = 72*12*512 + 24*12*512 + 12*4*4*64*4;
    prep_kernel<<<(total + 255)/256, 256, 0, stream>>>(qkv_w, proj_w, rpb, rel_idx, ws);
    qkva_kernel<<<4096, 512, 0, stream>>>(x, qkv_b, ws);
    proj_kernel<<<3136, 512, 0, stream>>>(proj_b, ws, (float*)d_out);
}